// Round 1
// baseline (2674.277 us; speedup 1.0000x reference)
//
#include <hip/hip_runtime.h>

#define NN 50000
#define NE 400000
#define DD 512
#define NLAYER 3

// ---------------- CSR build ----------------

__global__ void hist_kernel(const int* __restrict__ dst, int* __restrict__ deg) {
    int e = blockIdx.x * blockDim.x + threadIdx.x;
    if (e < NE) atomicAdd(&deg[dst[e]], 1);
}

__global__ void scan_kernel(const int* __restrict__ deg, int* __restrict__ offsets,
                            float* __restrict__ inv_deg) {
    __shared__ int sdata[1024];
    __shared__ int carry;
    if (threadIdx.x == 0) carry = 0;
    __syncthreads();
    const int tiles = (NN + 1023) / 1024;
    for (int t = 0; t < tiles; ++t) {
        int i = t * 1024 + threadIdx.x;
        int v = (i < NN) ? deg[i] : 0;
        sdata[threadIdx.x] = v;
        __syncthreads();
        // inclusive block scan
        for (int off = 1; off < 1024; off <<= 1) {
            int add = (threadIdx.x >= off) ? sdata[threadIdx.x - off] : 0;
            __syncthreads();
            sdata[threadIdx.x] += add;
            __syncthreads();
        }
        int incl = sdata[threadIdx.x];
        if (i < NN) {
            offsets[i] = carry + incl - v;     // exclusive
            inv_deg[i] = (v > 0) ? (1.0f / (float)v) : 0.0f;
        }
        __syncthreads();
        if (threadIdx.x == 1023) carry += sdata[1023];
        __syncthreads();
    }
    if (threadIdx.x == 0) offsets[NN] = NE;
}

__global__ void scatter_kernel(const int* __restrict__ src, const int* __restrict__ dst,
                               const float* __restrict__ w, const int* __restrict__ offsets,
                               int* __restrict__ cursor, int* __restrict__ ssrc,
                               float* __restrict__ sw) {
    int e = blockIdx.x * blockDim.x + threadIdx.x;
    if (e < NE) {
        int d = dst[e];
        int pos = offsets[d] + atomicAdd(&cursor[d], 1);
        ssrc[pos] = src[e];
        sw[pos] = w[e];
    }
}

// ---------------- mean aggregation (CSR gather) ----------------
// one block per node, 128 threads, each owns 4 consecutive dims (float4)
__global__ __launch_bounds__(128) void aggregate_kernel(
        const float* __restrict__ z, const int* __restrict__ ssrc,
        const float* __restrict__ sw, const int* __restrict__ offsets,
        const float* __restrict__ inv_deg, float* __restrict__ agg) {
    int n = blockIdx.x;
    int d4 = threadIdx.x * 4;
    int s0 = offsets[n], s1 = offsets[n + 1];
    float4 acc = make_float4(0.f, 0.f, 0.f, 0.f);
    for (int e = s0; e < s1; ++e) {
        int s = ssrc[e];
        float w = sw[e];
        float4 v = *(const float4*)&z[(size_t)s * DD + d4];
        acc.x = fmaf(w, v.x, acc.x);
        acc.y = fmaf(w, v.y, acc.y);
        acc.z = fmaf(w, v.z, acc.z);
        acc.w = fmaf(w, v.w, acc.w);
    }
    float inv = inv_deg[n];
    acc.x *= inv; acc.y *= inv; acc.z *= inv; acc.w *= inv;
    *(float4*)&agg[(size_t)n * DD + d4] = acc;
}

// ---------------- fused dual GEMM: out = relu(agg@Wl + z@Wr + bias) ----------------
// BM=BN=64, BK=16, 256 threads, 4x4 micro-tile per thread
__global__ __launch_bounds__(256) void gemm_fused(
        const float* __restrict__ agg, const float* __restrict__ z,
        const float* __restrict__ Wl, const float* __restrict__ Wr,
        const float* __restrict__ bias, float* __restrict__ out) {
    __shared__ float As[16][68];   // [k][m], padded
    __shared__ float Bs[16][68];   // [k][n], padded

    const int tid = threadIdx.x;
    const int tx = tid & 15;       // 16 cols of threads -> 64 output cols
    const int ty = tid >> 4;       // 16 rows of threads -> 64 output rows
    const int m0 = blockIdx.y * 64;
    const int n0 = blockIdx.x * 64;

    float acc[4][4] = {};

    for (int pair = 0; pair < 2; ++pair) {
        const float* __restrict__ A = pair ? z : agg;
        const float* __restrict__ W = pair ? Wr : Wl;
        for (int k0 = 0; k0 < DD; k0 += 16) {
            // stage A tile (64 rows x 16 k), transposed into As[k][m]
            {
                int row = tid >> 2;             // 0..63
                int kq  = (tid & 3) * 4;        // 0,4,8,12
                int gm = m0 + row;
                float4 v = make_float4(0.f, 0.f, 0.f, 0.f);
                if (gm < NN) v = *(const float4*)&A[(size_t)gm * DD + k0 + kq];
                As[kq + 0][row] = v.x;
                As[kq + 1][row] = v.y;
                As[kq + 2][row] = v.z;
                As[kq + 3][row] = v.w;
            }
            // stage B tile (16 k x 64 n)
            {
                int krow = tid >> 4;            // 0..15
                int nq = (tid & 15) * 4;        // 0..60
                float4 v = *(const float4*)&W[(size_t)(k0 + krow) * DD + n0 + nq];
                *(float4*)&Bs[krow][nq] = v;
            }
            __syncthreads();
            #pragma unroll
            for (int k = 0; k < 16; ++k) {
                float4 a4 = *(const float4*)&As[k][ty * 4];
                float4 b4 = *(const float4*)&Bs[k][tx * 4];
                float av[4] = {a4.x, a4.y, a4.z, a4.w};
                float bv[4] = {b4.x, b4.y, b4.z, b4.w};
                #pragma unroll
                for (int i = 0; i < 4; ++i)
                    #pragma unroll
                    for (int j = 0; j < 4; ++j)
                        acc[i][j] = fmaf(av[i], bv[j], acc[i][j]);
            }
            __syncthreads();
        }
    }

    // epilogue: bias + relu, float4 stores
    float4 bb = *(const float4*)&bias[n0 + tx * 4];
    #pragma unroll
    for (int i = 0; i < 4; ++i) {
        int gm = m0 + ty * 4 + i;
        if (gm < NN) {
            float4 o;
            o.x = acc[i][0] + bb.x;
            o.y = acc[i][1] + bb.y;
            o.z = acc[i][2] + bb.z;
            o.w = acc[i][3] + bb.w;
            o.x = o.x > 0.f ? o.x : 0.f;
            o.y = o.y > 0.f ? o.y : 0.f;
            o.z = o.z > 0.f ? o.z : 0.f;
            o.w = o.w > 0.f ? o.w : 0.f;
            *(float4*)&out[(size_t)gm * DD + n0 + tx * 4] = o;
        }
    }
}

extern "C" void kernel_launch(void* const* d_in, const int* in_sizes, int n_in,
                              void* d_out, int out_size, void* d_ws, size_t ws_size,
                              hipStream_t stream) {
    const float* x  = (const float*)d_in[0];
    const int*   ei = (const int*)d_in[1];
    const float* ew = (const float*)d_in[2];
    const float* Wl = (const float*)d_in[3];
    const float* Wr = (const float*)d_in[4];
    const float* b  = (const float*)d_in[5];
    float* out = (float*)d_out;

    const int* srcIdx = ei;          // edge_index[0]
    const int* dstIdx = ei + NE;     // edge_index[1]

    const size_t ND = (size_t)NN * DD;
    float* bufA = (float*)d_ws;
    float* bufB = bufA + ND;
    char* p = (char*)(bufB + ND);
    int* deg     = (int*)p;   p += sizeof(int) * NN;
    int* cursor  = (int*)p;   p += sizeof(int) * NN;       // contiguous with deg
    int* offsets = (int*)p;   p += sizeof(int) * (NN + 1);
    int* ssrc    = (int*)p;   p += sizeof(int) * NE;
    float* sw    = (float*)p; p += sizeof(float) * NE;
    float* inv_deg = (float*)p;

    // build CSR (deg & cursor zeroed together)
    hipMemsetAsync(deg, 0, sizeof(int) * 2 * NN, stream);
    hist_kernel<<<(NE + 255) / 256, 256, 0, stream>>>(dstIdx, deg);
    scan_kernel<<<1, 1024, 0, stream>>>(deg, offsets, inv_deg);
    scatter_kernel<<<(NE + 255) / 256, 256, 0, stream>>>(srcIdx, dstIdx, ew, offsets,
                                                          cursor, ssrc, sw);

    dim3 ggrid(DD / 64, (NN + 63) / 64);

    // layer 0: z=x, agg->d_out (scratch), out->bufA
    aggregate_kernel<<<NN, 128, 0, stream>>>(x, ssrc, sw, offsets, inv_deg, out);
    gemm_fused<<<ggrid, 256, 0, stream>>>(out, x, Wl, Wr, b, bufA);
    // layer 1: z=bufA, agg->d_out, out->bufB
    aggregate_kernel<<<NN, 128, 0, stream>>>(bufA, ssrc, sw, offsets, inv_deg, out);
    gemm_fused<<<ggrid, 256, 0, stream>>>(out, bufA, Wl + DD * DD, Wr + DD * DD, b + DD, bufB);
    // layer 2: z=bufB, agg->bufA, out->d_out
    aggregate_kernel<<<NN, 128, 0, stream>>>(bufB, ssrc, sw, offsets, inv_deg, bufA);
    gemm_fused<<<ggrid, 256, 0, stream>>>(bufA, bufB, Wl + 2 * DD * DD, Wr + 2 * DD * DD,
                                          b + 2 * DD, out);
}

// Round 2
// 1277.795 us; speedup vs baseline: 2.0929x; 2.0929x over previous
//
#include <hip/hip_runtime.h>

#define NN 50000
#define NE 400000
#define DD 512
#define MT 391   // ceil(NN/128)

typedef unsigned short ushort_t;
typedef __attribute__((ext_vector_type(8))) short bf16x8;
typedef __attribute__((ext_vector_type(4))) float f32x4;

#define GLD16(g, l) __builtin_amdgcn_global_load_lds( \
    (const __attribute__((address_space(1))) void*)(g), \
    (__attribute__((address_space(3))) void*)(l), 16, 0, 0)

__device__ __forceinline__ float bf2f(unsigned short u) {
    union { unsigned u; float f; } c; c.u = ((unsigned)u) << 16; return c.f;
}
__device__ __forceinline__ unsigned short f2bf(float f) {
    union { float f; unsigned u; } c; c.f = f;
    unsigned r = c.u + 0x7FFFu + ((c.u >> 16) & 1u);
    return (unsigned short)(r >> 16);
}
__device__ __forceinline__ void split2(float v, unsigned short& h, unsigned short& l) {
    h = f2bf(v);
    l = f2bf(v - bf2f(h));
}

// ---------------- CSR build ----------------

__global__ void hist_kernel(const int* __restrict__ dst, int* __restrict__ deg) {
    int e = blockIdx.x * blockDim.x + threadIdx.x;
    if (e < NE) atomicAdd(&deg[dst[e]], 1);
}

__global__ void scan_kernel(const int* __restrict__ deg, int* __restrict__ offsets,
                            float* __restrict__ inv_deg) {
    __shared__ int sdata[1024];
    __shared__ int carry;
    if (threadIdx.x == 0) carry = 0;
    __syncthreads();
    const int tiles = (NN + 1023) / 1024;
    for (int t = 0; t < tiles; ++t) {
        int i = t * 1024 + threadIdx.x;
        int v = (i < NN) ? deg[i] : 0;
        sdata[threadIdx.x] = v;
        __syncthreads();
        for (int off = 1; off < 1024; off <<= 1) {
            int add = (threadIdx.x >= off) ? sdata[threadIdx.x - off] : 0;
            __syncthreads();
            sdata[threadIdx.x] += add;
            __syncthreads();
        }
        int incl = sdata[threadIdx.x];
        if (i < NN) {
            offsets[i] = carry + incl - v;
            inv_deg[i] = (v > 0) ? (1.0f / (float)v) : 0.0f;
        }
        __syncthreads();
        if (threadIdx.x == 1023) carry += sdata[1023];
        __syncthreads();
    }
    if (threadIdx.x == 0) offsets[NN] = NE;
}

__global__ void scatter_kernel(const int* __restrict__ src, const int* __restrict__ dst,
                               const float* __restrict__ w, const int* __restrict__ offsets,
                               int* __restrict__ cursor, int* __restrict__ ssrc,
                               float* __restrict__ sw) {
    int e = blockIdx.x * blockDim.x + threadIdx.x;
    if (e < NE) {
        int d = dst[e];
        int pos = offsets[d] + atomicAdd(&cursor[d], 1);
        ssrc[pos] = src[e];
        sw[pos] = w[e];
    }
}

// ---------------- input conversions ----------------

__global__ void split_x_kernel(const float* __restrict__ x, ushort_t* __restrict__ xh,
                               ushort_t* __restrict__ xl) {
    const int total = NN * DD / 4;
    for (int i = blockIdx.x * blockDim.x + threadIdx.x; i < total; i += gridDim.x * blockDim.x) {
        float4 v = ((const float4*)x)[i];
        ushort4 h, l;
        split2(v.x, h.x, l.x); split2(v.y, h.y, l.y);
        split2(v.z, h.z, l.z); split2(v.w, h.w, l.w);
        ((ushort4*)xh)[i] = h; ((ushort4*)xl)[i] = l;
    }
}

// transpose + split weights: wt layout [layer][WlT_h, WlT_l, WrT_h, WrT_l], each [n][k]
__global__ void split_wt_kernel(const float* __restrict__ Wl, const float* __restrict__ Wr,
                                ushort_t* __restrict__ wt) {
    __shared__ float tile[32][33];
    int mat = blockIdx.z;              // layer*2 + (0=Wl,1=Wr)
    int layer = mat >> 1;
    const float* W = (mat & 1) ? (Wr + (size_t)layer * DD * DD) : (Wl + (size_t)layer * DD * DD);
    ushort_t* oh = wt + ((size_t)layer * 4 + (size_t)(mat & 1) * 2) * DD * DD;
    ushort_t* ol = oh + (size_t)DD * DD;
    int k0 = blockIdx.y * 32, n0 = blockIdx.x * 32;
    #pragma unroll
    for (int r = 0; r < 4; ++r)
        tile[threadIdx.y * 4 + r][threadIdx.x] =
            W[(size_t)(k0 + threadIdx.y * 4 + r) * DD + n0 + threadIdx.x];
    __syncthreads();
    #pragma unroll
    for (int r = 0; r < 4; ++r) {
        int n = n0 + threadIdx.y * 4 + r, k = k0 + threadIdx.x;
        unsigned short h, l;
        split2(tile[threadIdx.x][threadIdx.y * 4 + r], h, l);
        oh[(size_t)n * DD + k] = h;
        ol[(size_t)n * DD + k] = l;
    }
}

// ---------------- mean aggregation (CSR gather, bf16 h/l in & out) ----------------

__global__ __launch_bounds__(128) void aggregate_kernel(
        const ushort_t* __restrict__ zh, const ushort_t* __restrict__ zl,
        const int* __restrict__ ssrc, const float* __restrict__ sw,
        const int* __restrict__ offsets, const float* __restrict__ inv_deg,
        ushort_t* __restrict__ aggh, ushort_t* __restrict__ aggl) {
    int n = blockIdx.x;
    int d4 = threadIdx.x * 4;
    int s0 = offsets[n], s1 = offsets[n + 1];
    float a0 = 0.f, a1 = 0.f, a2 = 0.f, a3 = 0.f;
    for (int e = s0; e < s1; ++e) {
        int s = ssrc[e];
        float w = sw[e];
        ushort4 h = *(const ushort4*)&zh[(size_t)s * DD + d4];
        ushort4 l = *(const ushort4*)&zl[(size_t)s * DD + d4];
        a0 = fmaf(w, bf2f(h.x) + bf2f(l.x), a0);
        a1 = fmaf(w, bf2f(h.y) + bf2f(l.y), a1);
        a2 = fmaf(w, bf2f(h.z) + bf2f(l.z), a2);
        a3 = fmaf(w, bf2f(h.w) + bf2f(l.w), a3);
    }
    float inv = inv_deg[n];
    a0 *= inv; a1 *= inv; a2 *= inv; a3 *= inv;
    ushort4 oh, ol;
    split2(a0, oh.x, ol.x); split2(a1, oh.y, ol.y);
    split2(a2, oh.z, ol.z); split2(a3, oh.w, ol.w);
    *(ushort4*)&aggh[(size_t)n * DD + d4] = oh;
    *(ushort4*)&aggl[(size_t)n * DD + d4] = ol;
}

// ---------------- split-bf16 MFMA GEMM ----------------
// out = relu(agg@Wl + z@Wr + b); A.B ~= Ah.Bh + Ah.Bl + Al.Bh
// 128x128 tile, BK=64, 4 waves (each 64x64 = 4x4 frags of 16x16x32)
// LDS: Ah,Al,Bh,Bl tiles [128 rows][64 bf16 = 128B], XOR slot-swizzled via
// pre-swizzled global source addresses (global_load_lds writes linearly).

template<bool FINAL>
__global__ __launch_bounds__(256) void gemm_mfma(
        const ushort_t* __restrict__ aggh, const ushort_t* __restrict__ aggl,
        const ushort_t* __restrict__ zh, const ushort_t* __restrict__ zl,
        const ushort_t* __restrict__ wt,   // this layer: WlTh, WlTl, WrTh, WrTl
        const float* __restrict__ bias,
        ushort_t* __restrict__ outh, ushort_t* __restrict__ outl,
        float* __restrict__ outf) {
    __shared__ char smem[65536];
    const int AH = 0, AL = 16384, BH = 32768, BL = 49152;

    const int tid = threadIdx.x;
    const int lane = tid & 63;
    const int w = tid >> 6;
    const int wr = w >> 1, wc = w & 1;
    const int m0 = blockIdx.y * 128;
    const int n0 = blockIdx.x * 128;

    // staging constants: lane covers row rbase+(lane>>3), 16B slot (lane&7)
    const int rsub = lane >> 3;
    const int sl = (lane & 7) ^ rsub;       // swizzled source slot
    int offA[4], offB[4];
    #pragma unroll
    for (int j = 0; j < 4; ++j) {
        int q = w * 4 + j;
        int ra = m0 + q * 8 + rsub;
        if (ra >= NN) ra = NN - 1;          // clamp tail rows (outputs discarded)
        offA[j] = ra * DD + sl * 8;
        int rb = n0 + q * 8 + rsub;
        offB[j] = rb * DD + sl * 8;
    }

    // ds_read constants
    const int rlo = lane & 15;
    const int khi = lane >> 4;              // 0..3
    const int sw7 = rlo & 7;
    int aRow[4], bRow[4];
    #pragma unroll
    for (int i = 0; i < 4; ++i) {
        aRow[i] = (wr * 64 + i * 16 + rlo) * 128;
        bRow[i] = (wc * 64 + i * 16 + rlo) * 128;
    }

    f32x4 acc[4][4];
    #pragma unroll
    for (int mi = 0; mi < 4; ++mi)
        #pragma unroll
        for (int ni = 0; ni < 4; ++ni)
            acc[mi][ni] = f32x4{0.f, 0.f, 0.f, 0.f};

    #pragma unroll
    for (int pass = 0; pass < 2; ++pass) {
        const ushort_t* Ah = pass ? zh : aggh;
        const ushort_t* Al = pass ? zl : aggl;
        const ushort_t* Bh = wt + (size_t)(pass ? 2 : 0) * DD * DD;
        const ushort_t* Bl = Bh + (size_t)DD * DD;
        for (int k0 = 0; k0 < DD; k0 += 64) {
            #pragma unroll
            for (int j = 0; j < 4; ++j) {
                int q = (w * 4 + j) * 1024;
                GLD16(Ah + offA[j] + k0, smem + AH + q);
                GLD16(Al + offA[j] + k0, smem + AL + q);
                GLD16(Bh + offB[j] + k0, smem + BH + q);
                GLD16(Bl + offB[j] + k0, smem + BL + q);
            }
            __syncthreads();
            #pragma unroll
            for (int kk = 0; kk < 2; ++kk) {
                const int pa = ((kk * 4 + khi) ^ sw7) * 16;
                bf16x8 a_h[4], a_l[4], b_h[4], b_l[4];
                #pragma unroll
                for (int i = 0; i < 4; ++i) {
                    a_h[i] = *(const bf16x8*)(smem + AH + aRow[i] + pa);
                    a_l[i] = *(const bf16x8*)(smem + AL + aRow[i] + pa);
                    b_h[i] = *(const bf16x8*)(smem + BH + bRow[i] + pa);
                    b_l[i] = *(const bf16x8*)(smem + BL + bRow[i] + pa);
                }
                #pragma unroll
                for (int mi = 0; mi < 4; ++mi)
                    #pragma unroll
                    for (int ni = 0; ni < 4; ++ni) {
                        acc[mi][ni] = __builtin_amdgcn_mfma_f32_16x16x32_bf16(
                            a_h[mi], b_h[ni], acc[mi][ni], 0, 0, 0);
                        acc[mi][ni] = __builtin_amdgcn_mfma_f32_16x16x32_bf16(
                            a_h[mi], b_l[ni], acc[mi][ni], 0, 0, 0);
                        acc[mi][ni] = __builtin_amdgcn_mfma_f32_16x16x32_bf16(
                            a_l[mi], b_h[ni], acc[mi][ni], 0, 0, 0);
                    }
            }
            __syncthreads();
        }
    }

    // epilogue: bias + relu; C/D layout col=lane&15, row=(lane>>4)*4+reg
    float bv[4];
    #pragma unroll
    for (int ni = 0; ni < 4; ++ni)
        bv[ni] = bias[n0 + wc * 64 + ni * 16 + rlo];
    #pragma unroll
    for (int mi = 0; mi < 4; ++mi) {
        #pragma unroll
        for (int j = 0; j < 4; ++j) {
            int row = m0 + wr * 64 + mi * 16 + khi * 4 + j;
            if (row < NN) {
                #pragma unroll
                for (int ni = 0; ni < 4; ++ni) {
                    int col = n0 + wc * 64 + ni * 16 + rlo;
                    float v = acc[mi][ni][j] + bv[ni];
                    v = v > 0.f ? v : 0.f;
                    if (FINAL) {
                        outf[(size_t)row * DD + col] = v;
                    } else {
                        unsigned short h, l;
                        split2(v, h, l);
                        outh[(size_t)row * DD + col] = h;
                        outl[(size_t)row * DD + col] = l;
                    }
                }
            }
        }
    }
}

extern "C" void kernel_launch(void* const* d_in, const int* in_sizes, int n_in,
                              void* d_out, int out_size, void* d_ws, size_t ws_size,
                              hipStream_t stream) {
    const float* x  = (const float*)d_in[0];
    const int*   ei = (const int*)d_in[1];
    const float* ew = (const float*)d_in[2];
    const float* Wl = (const float*)d_in[3];
    const float* Wr = (const float*)d_in[4];
    const float* b  = (const float*)d_in[5];

    const int* srcIdx = ei;
    const int* dstIdx = ei + NE;

    const size_t ND = (size_t)NN * DD;
    char* p = (char*)d_ws;
    ushort_t* z1h  = (ushort_t*)p; p += ND * 2;
    ushort_t* z1l  = (ushort_t*)p; p += ND * 2;   // z1h..z1l region doubles as final f32 out
    ushort_t* aggh = (ushort_t*)p; p += ND * 2;
    ushort_t* aggl = (ushort_t*)p; p += ND * 2;
    ushort_t* wt   = (ushort_t*)p; p += (size_t)12 * DD * DD * 2;
    int* deg      = (int*)p; p += sizeof(int) * NN;
    int* cursor   = (int*)p; p += sizeof(int) * NN;      // contiguous with deg
    int* ssrc     = (int*)p; p += sizeof(int) * NE;
    float* sw     = (float*)p; p += sizeof(float) * NE;
    float* invdeg = (float*)p; p += sizeof(float) * NN;
    int* offsets  = (int*)p; p += sizeof(int) * (NN + 1);

    // x (=z0) pair lives in d_out (scratch until the final copy): exactly fits
    ushort_t* xh = (ushort_t*)d_out;
    ushort_t* xl = xh + ND;
    float* foutTmp = (float*)z1h;

    // CSR build
    hipMemsetAsync(deg, 0, sizeof(int) * 2 * NN, stream);
    hist_kernel<<<(NE + 255) / 256, 256, 0, stream>>>(dstIdx, deg);
    scan_kernel<<<1, 1024, 0, stream>>>(deg, offsets, invdeg);
    scatter_kernel<<<(NE + 255) / 256, 256, 0, stream>>>(srcIdx, dstIdx, ew, offsets,
                                                          cursor, ssrc, sw);
    // conversions
    split_x_kernel<<<4096, 256, 0, stream>>>(x, xh, xl);
    split_wt_kernel<<<dim3(16, 16, 6), dim3(32, 8), 0, stream>>>(Wl, Wr, wt);

    dim3 ggrid(4, MT);
    const size_t WTL = (size_t)4 * DD * DD;

    // layer 0: z = x(pair in d_out) -> z1 (ws)
    aggregate_kernel<<<NN, 128, 0, stream>>>(xh, xl, ssrc, sw, offsets, invdeg, aggh, aggl);
    gemm_mfma<false><<<ggrid, 256, 0, stream>>>(aggh, aggl, xh, xl, wt, b,
                                                z1h, z1l, nullptr);
    // layer 1: z = z1 -> z2 (reuse x pair region in d_out)
    aggregate_kernel<<<NN, 128, 0, stream>>>(z1h, z1l, ssrc, sw, offsets, invdeg, aggh, aggl);
    gemm_mfma<false><<<ggrid, 256, 0, stream>>>(aggh, aggl, z1h, z1l, wt + WTL, b + DD,
                                                xh, xl, nullptr);
    // layer 2: z = z2 -> f32 staged in ws (z1 region), then copy to d_out
    aggregate_kernel<<<NN, 128, 0, stream>>>(xh, xl, ssrc, sw, offsets, invdeg, aggh, aggl);
    gemm_mfma<true><<<ggrid, 256, 0, stream>>>(aggh, aggl, xh, xl, wt + 2 * WTL, b + 2 * DD,
                                               nullptr, nullptr, foutTmp);
    hipMemcpyAsync(d_out, foutTmp, ND * sizeof(float), hipMemcpyDeviceToDevice, stream);
}

// Round 3
// 835.486 us; speedup vs baseline: 3.2009x; 1.5294x over previous
//
#include <hip/hip_runtime.h>

#define NN 50000
#define NE 400000
#define DD 512
#define MT 391   // ceil(NN/128)

typedef unsigned short ushort_t;
typedef __attribute__((ext_vector_type(8))) short bf16x8;
typedef __attribute__((ext_vector_type(8))) unsigned short u16x8;
typedef __attribute__((ext_vector_type(4))) float f32x4;

#define GLD16(g, l) __builtin_amdgcn_global_load_lds( \
    (const __attribute__((address_space(1))) void*)(g), \
    (__attribute__((address_space(3))) void*)(l), 16, 0, 0)

__device__ __forceinline__ float bf2f(unsigned short u) {
    union { unsigned u; float f; } c; c.u = ((unsigned)u) << 16; return c.f;
}
__device__ __forceinline__ unsigned short f2bf(float f) {
    union { float f; unsigned u; } c; c.f = f;
    unsigned r = c.u + 0x7FFFu + ((c.u >> 16) & 1u);
    return (unsigned short)(r >> 16);
}
__device__ __forceinline__ void split2(float v, unsigned short& h, unsigned short& l) {
    h = f2bf(v);
    l = f2bf(v - bf2f(h));
}

// ---------------- CSR build ----------------

__global__ void hist_kernel(const int* __restrict__ dst, int* __restrict__ deg) {
    int e = blockIdx.x * blockDim.x + threadIdx.x;
    if (e < NE) atomicAdd(&deg[dst[e]], 1);
}

__global__ void scan_kernel(const int* __restrict__ deg, int* __restrict__ offsets,
                            float* __restrict__ inv_deg) {
    __shared__ int sdata[1024];
    __shared__ int carry;
    if (threadIdx.x == 0) carry = 0;
    __syncthreads();
    const int tiles = (NN + 1023) / 1024;
    for (int t = 0; t < tiles; ++t) {
        int i = t * 1024 + threadIdx.x;
        int v = (i < NN) ? deg[i] : 0;
        sdata[threadIdx.x] = v;
        __syncthreads();
        for (int off = 1; off < 1024; off <<= 1) {
            int add = (threadIdx.x >= off) ? sdata[threadIdx.x - off] : 0;
            __syncthreads();
            sdata[threadIdx.x] += add;
            __syncthreads();
        }
        int incl = sdata[threadIdx.x];
        if (i < NN) {
            offsets[i] = carry + incl - v;
            inv_deg[i] = (v > 0) ? (1.0f / (float)v) : 0.0f;
        }
        __syncthreads();
        if (threadIdx.x == 1023) carry += sdata[1023];
        __syncthreads();
    }
    if (threadIdx.x == 0) offsets[NN] = NE;
}

__global__ void scatter_kernel(const int* __restrict__ src, const int* __restrict__ dst,
                               const float* __restrict__ w, const int* __restrict__ offsets,
                               int* __restrict__ cursor, int* __restrict__ ssrc,
                               float* __restrict__ sw) {
    int e = blockIdx.x * blockDim.x + threadIdx.x;
    if (e < NE) {
        int d = dst[e];
        int pos = offsets[d] + atomicAdd(&cursor[d], 1);
        ssrc[pos] = src[e];
        sw[pos] = w[e];
    }
}

// ---------------- input conversions ----------------

// x -> bf16 (single)
__global__ void convert_x_kernel(const float* __restrict__ x, ushort_t* __restrict__ xh) {
    const int total = NN * DD / 8;
    for (int i = blockIdx.x * blockDim.x + threadIdx.x; i < total; i += gridDim.x * blockDim.x) {
        float4 v1 = ((const float4*)x)[2 * i];
        float4 v2 = ((const float4*)x)[2 * i + 1];
        u16x8 o;
        o[0] = f2bf(v1.x); o[1] = f2bf(v1.y); o[2] = f2bf(v1.z); o[3] = f2bf(v1.w);
        o[4] = f2bf(v2.x); o[5] = f2bf(v2.y); o[6] = f2bf(v2.z); o[7] = f2bf(v2.w);
        ((u16x8*)xh)[i] = o;
    }
}

// transpose + split weights: wt layout [layer][WlT_h, WlT_l, WrT_h, WrT_l], each [n][k]
__global__ void split_wt_kernel(const float* __restrict__ Wl, const float* __restrict__ Wr,
                                ushort_t* __restrict__ wt) {
    __shared__ float tile[32][33];
    int mat = blockIdx.z;              // layer*2 + (0=Wl,1=Wr)
    int layer = mat >> 1;
    const float* W = (mat & 1) ? (Wr + (size_t)layer * DD * DD) : (Wl + (size_t)layer * DD * DD);
    ushort_t* oh = wt + ((size_t)layer * 4 + (size_t)(mat & 1) * 2) * DD * DD;
    ushort_t* ol = oh + (size_t)DD * DD;
    int k0 = blockIdx.y * 32, n0 = blockIdx.x * 32;
    #pragma unroll
    for (int r = 0; r < 4; ++r)
        tile[threadIdx.y * 4 + r][threadIdx.x] =
            W[(size_t)(k0 + threadIdx.y * 4 + r) * DD + n0 + threadIdx.x];
    __syncthreads();
    #pragma unroll
    for (int r = 0; r < 4; ++r) {
        int n = n0 + threadIdx.y * 4 + r, k = k0 + threadIdx.x;
        unsigned short h, l;
        split2(tile[threadIdx.x][threadIdx.y * 4 + r], h, l);
        oh[(size_t)n * DD + k] = h;
        ol[(size_t)n * DD + k] = l;
    }
}

// ---------------- mean aggregation: wave per node, bf16 in/out ----------------

__global__ __launch_bounds__(256) void aggregate_kernel(
        const ushort_t* __restrict__ zh, const int* __restrict__ ssrc,
        const float* __restrict__ sw, const int* __restrict__ offsets,
        const float* __restrict__ inv_deg, ushort_t* __restrict__ aggh) {
    int node = blockIdx.x * 4 + (threadIdx.x >> 6);
    if (node >= NN) return;
    int lane = threadIdx.x & 63;
    int d8 = lane * 8;
    int s0 = offsets[node], s1 = offsets[node + 1];
    float a[8] = {0.f, 0.f, 0.f, 0.f, 0.f, 0.f, 0.f, 0.f};
    for (int e = s0; e < s1; ++e) {
        int s = ssrc[e];
        float w = sw[e];
        u16x8 v = *(const u16x8*)&zh[(size_t)s * DD + d8];
        #pragma unroll
        for (int j = 0; j < 8; ++j) a[j] = fmaf(w, bf2f(v[j]), a[j]);
    }
    float inv = inv_deg[node];
    u16x8 o;
    #pragma unroll
    for (int j = 0; j < 8; ++j) o[j] = f2bf(a[j] * inv);
    *(u16x8*)&aggh[(size_t)node * DD + d8] = o;
}

// ---------------- split-bf16 MFMA GEMM ----------------
// out = relu(agg@Wl + z@Wr + b); activations single bf16, weights h/l pair:
// each matmul = A.Bh + A.Bl (2 MFMA products).
// 128x128 tile, BK=64, 4 waves (each 64x64 = 4x4 frags of 16x16x32)
// LDS: A, Bh, Bl tiles [128 rows][64 bf16 = 128B], XOR slot-swizzled via
// pre-swizzled global source addresses (global_load_lds writes linearly).
// XCD-chunked bijective blockIdx swizzle (m204): 4 N-blocks sharing an
// A-strip land on the same XCD -> A read from HBM once per XCD.

template<bool FINAL>
__global__ __launch_bounds__(256) void gemm_mfma(
        const ushort_t* __restrict__ aggh, const ushort_t* __restrict__ zh,
        const ushort_t* __restrict__ wt,   // this layer: WlTh, WlTl, WrTh, WrTl
        const float* __restrict__ bias,
        ushort_t* __restrict__ outh, float* __restrict__ outf) {
    __shared__ char smem[49152];
    const int AT = 0, BH = 16384, BL = 32768;

    const int tid = threadIdx.x;
    const int lane = tid & 63;
    const int w = tid >> 6;
    const int wr = w >> 1, wc = w & 1;

    // XCD-chunked bijective swizzle: orig -> chunked wgid (nwg=1564=8*195+4)
    const int orig = blockIdx.y * gridDim.x + blockIdx.x;   // x-fastest linear id
    const int q = 195, r = 4;
    const int xcd = orig & 7, kpos = orig >> 3;
    const int wg = (xcd < r ? xcd * (q + 1) : r * (q + 1) + (xcd - r) * q) + kpos;
    const int m0 = (wg >> 2) * 128;
    const int n0 = (wg & 3) * 128;

    // staging: lane covers row q*8+(lane>>3), swizzled 16B slot
    const int rsub = lane >> 3;
    const int sl = (lane & 7) ^ rsub;
    int offA[4], offB[4];
    #pragma unroll
    for (int j = 0; j < 4; ++j) {
        int qq = w * 4 + j;
        int ra = m0 + qq * 8 + rsub;
        if (ra >= NN) ra = NN - 1;          // clamp tail rows (outputs discarded)
        offA[j] = ra * DD + sl * 8;
        int rb = n0 + qq * 8 + rsub;
        offB[j] = rb * DD + sl * 8;
    }

    // ds_read constants
    const int rlo = lane & 15;
    const int khi = lane >> 4;              // 0..3
    const int sw7 = rlo & 7;
    int aRow[4], bRow[4];
    #pragma unroll
    for (int i = 0; i < 4; ++i) {
        aRow[i] = (wr * 64 + i * 16 + rlo) * 128;
        bRow[i] = (wc * 64 + i * 16 + rlo) * 128;
    }

    f32x4 acc[4][4];
    #pragma unroll
    for (int mi = 0; mi < 4; ++mi)
        #pragma unroll
        for (int ni = 0; ni < 4; ++ni)
            acc[mi][ni] = f32x4{0.f, 0.f, 0.f, 0.f};

    #pragma unroll
    for (int pass = 0; pass < 2; ++pass) {
        const ushort_t* A  = pass ? zh : aggh;
        const ushort_t* Bh = wt + (size_t)(pass ? 2 : 0) * DD * DD;
        const ushort_t* Bl = Bh + (size_t)DD * DD;
        for (int k0 = 0; k0 < DD; k0 += 64) {
            #pragma unroll
            for (int j = 0; j < 4; ++j) {
                int qo = (w * 4 + j) * 1024;
                GLD16(A + offA[j] + k0, smem + AT + qo);
                GLD16(Bh + offB[j] + k0, smem + BH + qo);
                GLD16(Bl + offB[j] + k0, smem + BL + qo);
            }
            __syncthreads();
            #pragma unroll
            for (int kk = 0; kk < 2; ++kk) {
                const int pa = ((kk * 4 + khi) ^ sw7) * 16;
                bf16x8 a_f[4], b_h[4], b_l[4];
                #pragma unroll
                for (int i = 0; i < 4; ++i) {
                    a_f[i] = *(const bf16x8*)(smem + AT + aRow[i] + pa);
                    b_h[i] = *(const bf16x8*)(smem + BH + bRow[i] + pa);
                    b_l[i] = *(const bf16x8*)(smem + BL + bRow[i] + pa);
                }
                #pragma unroll
                for (int mi = 0; mi < 4; ++mi)
                    #pragma unroll
                    for (int ni = 0; ni < 4; ++ni) {
                        acc[mi][ni] = __builtin_amdgcn_mfma_f32_16x16x32_bf16(
                            a_f[mi], b_h[ni], acc[mi][ni], 0, 0, 0);
                        acc[mi][ni] = __builtin_amdgcn_mfma_f32_16x16x32_bf16(
                            a_f[mi], b_l[ni], acc[mi][ni], 0, 0, 0);
                    }
            }
            __syncthreads();
        }
    }

    // epilogue: bias + relu; C/D layout col=lane&15, row=(lane>>4)*4+reg
    float bv[4];
    #pragma unroll
    for (int ni = 0; ni < 4; ++ni)
        bv[ni] = bias[n0 + wc * 64 + ni * 16 + rlo];
    #pragma unroll
    for (int mi = 0; mi < 4; ++mi) {
        #pragma unroll
        for (int j = 0; j < 4; ++j) {
            int row = m0 + wr * 64 + mi * 16 + khi * 4 + j;
            if (row < NN) {
                #pragma unroll
                for (int ni = 0; ni < 4; ++ni) {
                    int col = n0 + wc * 64 + ni * 16 + rlo;
                    float v = acc[mi][ni][j] + bv[ni];
                    v = v > 0.f ? v : 0.f;
                    if (FINAL) outf[(size_t)row * DD + col] = v;
                    else       outh[(size_t)row * DD + col] = f2bf(v);
                }
            }
        }
    }
}

extern "C" void kernel_launch(void* const* d_in, const int* in_sizes, int n_in,
                              void* d_out, int out_size, void* d_ws, size_t ws_size,
                              hipStream_t stream) {
    const float* x  = (const float*)d_in[0];
    const int*   ei = (const int*)d_in[1];
    const float* ew = (const float*)d_in[2];
    const float* Wl = (const float*)d_in[3];
    const float* Wr = (const float*)d_in[4];
    const float* b  = (const float*)d_in[5];
    float* out = (float*)d_out;

    const int* srcIdx = ei;
    const int* dstIdx = ei + NE;

    const size_t ND = (size_t)NN * DD;
    char* p = (char*)d_ws;
    ushort_t* zA   = (ushort_t*)p; p += ND * 2;
    ushort_t* zB   = (ushort_t*)p; p += ND * 2;
    ushort_t* aggA = (ushort_t*)p; p += ND * 2;
    ushort_t* wt   = (ushort_t*)p; p += (size_t)12 * DD * DD * 2;
    int* deg      = (int*)p; p += sizeof(int) * NN;
    int* cursor   = (int*)p; p += sizeof(int) * NN;      // contiguous with deg
    int* ssrc     = (int*)p; p += sizeof(int) * NE;
    float* sw     = (float*)p; p += sizeof(float) * NE;
    float* invdeg = (float*)p; p += sizeof(float) * NN;
    int* offsets  = (int*)p; p += sizeof(int) * (NN + 1);

    // CSR build
    hipMemsetAsync(deg, 0, sizeof(int) * 2 * NN, stream);
    hist_kernel<<<(NE + 255) / 256, 256, 0, stream>>>(dstIdx, deg);
    scan_kernel<<<1, 1024, 0, stream>>>(deg, offsets, invdeg);
    scatter_kernel<<<(NE + 255) / 256, 256, 0, stream>>>(srcIdx, dstIdx, ew, offsets,
                                                          cursor, ssrc, sw);
    // conversions
    convert_x_kernel<<<2048, 256, 0, stream>>>(x, zA);
    split_wt_kernel<<<dim3(16, 16, 6), dim3(32, 8), 0, stream>>>(Wl, Wr, wt);

    dim3 ggrid(4, MT);
    dim3 agrid((NN + 3) / 4);
    const size_t WTL = (size_t)4 * DD * DD;

    // layer 0: z = zA(x) -> zB
    aggregate_kernel<<<agrid, 256, 0, stream>>>(zA, ssrc, sw, offsets, invdeg, aggA);
    gemm_mfma<false><<<ggrid, 256, 0, stream>>>(aggA, zA, wt, b, zB, nullptr);
    // layer 1: z = zB -> zA
    aggregate_kernel<<<agrid, 256, 0, stream>>>(zB, ssrc, sw, offsets, invdeg, aggA);
    gemm_mfma<false><<<ggrid, 256, 0, stream>>>(aggA, zB, wt + WTL, b + DD, zA, nullptr);
    // layer 2: z = zA -> d_out (f32, direct)
    aggregate_kernel<<<agrid, 256, 0, stream>>>(zA, ssrc, sw, offsets, invdeg, aggA);
    gemm_mfma<true><<<ggrid, 256, 0, stream>>>(aggA, zA, wt + 2 * WTL, b + 2 * DD,
                                               nullptr, out);
}

// Round 4
// 749.351 us; speedup vs baseline: 3.5688x; 1.1149x over previous
//
#include <hip/hip_runtime.h>

#define NN 50000
#define NE 400000
#define DD 512
#define MT 391   // ceil(NN/128)
#define SB 49    // ceil(NN/1024) scan blocks

typedef unsigned short ushort_t;
typedef __attribute__((ext_vector_type(8))) short bf16x8;
typedef __attribute__((ext_vector_type(8))) unsigned short u16x8;
typedef __attribute__((ext_vector_type(4))) float f32x4;

#define GLD16(g, l) __builtin_amdgcn_global_load_lds( \
    (const __attribute__((address_space(1))) void*)(g), \
    (__attribute__((address_space(3))) void*)(l), 16, 0, 0)

__device__ __forceinline__ float bf2f(unsigned short u) {
    union { unsigned u; float f; } c; c.u = ((unsigned)u) << 16; return c.f;
}
__device__ __forceinline__ unsigned short f2bf(float f) {
    union { float f; unsigned u; } c; c.f = f;
    unsigned r = c.u + 0x7FFFu + ((c.u >> 16) & 1u);
    return (unsigned short)(r >> 16);
}
__device__ __forceinline__ void split2(float v, unsigned short& h, unsigned short& l) {
    h = f2bf(v);
    l = f2bf(v - bf2f(h));
}

// ---------------- CSR build ----------------

__global__ void hist_kernel(const int* __restrict__ dst, int* __restrict__ deg) {
    int e = blockIdx.x * blockDim.x + threadIdx.x;
    if (e < NE) atomicAdd(&deg[dst[e]], 1);
}

// parallel scan, 3 stages
__global__ __launch_bounds__(1024) void scan_local(const int* __restrict__ deg,
                                                   int* __restrict__ offs,
                                                   int* __restrict__ bsum) {
    __shared__ int sdata[1024];
    int i = blockIdx.x * 1024 + threadIdx.x;
    int v = (i < NN) ? deg[i] : 0;
    sdata[threadIdx.x] = v;
    __syncthreads();
    for (int off = 1; off < 1024; off <<= 1) {
        int add = (threadIdx.x >= off) ? sdata[threadIdx.x - off] : 0;
        __syncthreads();
        sdata[threadIdx.x] += add;
        __syncthreads();
    }
    if (i < NN) offs[i] = sdata[threadIdx.x] - v;      // local exclusive
    if (threadIdx.x == 1023) bsum[blockIdx.x] = sdata[1023];
}

__global__ void scan_carry(int* __restrict__ bsum) {    // exclusive scan of SB values
    int lane = threadIdx.x;
    int orig = (lane < SB) ? bsum[lane] : 0;
    int v = orig;
    #pragma unroll
    for (int off = 1; off < 64; off <<= 1) {
        int n = __shfl_up(v, off, 64);
        if (lane >= off) v += n;
    }
    if (lane < SB) bsum[lane] = v - orig;
}

__global__ __launch_bounds__(1024) void scan_apply(const int* __restrict__ deg,
                                                   const int* __restrict__ bsum,
                                                   int* __restrict__ offs,
                                                   float* __restrict__ inv_deg) {
    int i = blockIdx.x * 1024 + threadIdx.x;
    if (i < NN) {
        offs[i] += bsum[blockIdx.x];
        int d = deg[i];
        inv_deg[i] = (d > 0) ? (1.0f / (float)d) : 0.0f;
    }
    if (i == 0) offs[NN] = NE;
}

__global__ void scatter_kernel(const int* __restrict__ src, const int* __restrict__ dst,
                               const float* __restrict__ w, const int* __restrict__ offsets,
                               int* __restrict__ cursor, int2* __restrict__ esw) {
    int e = blockIdx.x * blockDim.x + threadIdx.x;
    if (e < NE) {
        int d = dst[e];
        int pos = offsets[d] + atomicAdd(&cursor[d], 1);
        esw[pos] = make_int2(src[e], __float_as_int(w[e]));
    }
}

// ---------------- input conversions ----------------

__global__ void convert_x_kernel(const float* __restrict__ x, ushort_t* __restrict__ xh) {
    const int total = NN * DD / 8;
    for (int i = blockIdx.x * blockDim.x + threadIdx.x; i < total; i += gridDim.x * blockDim.x) {
        float4 v1 = ((const float4*)x)[2 * i];
        float4 v2 = ((const float4*)x)[2 * i + 1];
        u16x8 o;
        o[0] = f2bf(v1.x); o[1] = f2bf(v1.y); o[2] = f2bf(v1.z); o[3] = f2bf(v1.w);
        o[4] = f2bf(v2.x); o[5] = f2bf(v2.y); o[6] = f2bf(v2.z); o[7] = f2bf(v2.w);
        ((u16x8*)xh)[i] = o;
    }
}

// transpose + split weights: wt layout [layer][WlT_h, WlT_l, WrT_h, WrT_l], each [n][k]
__global__ void split_wt_kernel(const float* __restrict__ Wl, const float* __restrict__ Wr,
                                ushort_t* __restrict__ wt) {
    __shared__ float tile[32][33];
    int mat = blockIdx.z;              // layer*2 + (0=Wl,1=Wr)
    int layer = mat >> 1;
    const float* W = (mat & 1) ? (Wr + (size_t)layer * DD * DD) : (Wl + (size_t)layer * DD * DD);
    ushort_t* oh = wt + ((size_t)layer * 4 + (size_t)(mat & 1) * 2) * DD * DD;
    ushort_t* ol = oh + (size_t)DD * DD;
    int k0 = blockIdx.y * 32, n0 = blockIdx.x * 32;
    #pragma unroll
    for (int r = 0; r < 4; ++r)
        tile[threadIdx.y * 4 + r][threadIdx.x] =
            W[(size_t)(k0 + threadIdx.y * 4 + r) * DD + n0 + threadIdx.x];
    __syncthreads();
    #pragma unroll
    for (int r = 0; r < 4; ++r) {
        int n = n0 + threadIdx.y * 4 + r, k = k0 + threadIdx.x;
        unsigned short h, l;
        split2(tile[threadIdx.x][threadIdx.y * 4 + r], h, l);
        oh[(size_t)n * DD + k] = h;
        ol[(size_t)n * DD + k] = l;
    }
}

// ---------------- mean aggregation: wave per node, 4-edge unrolled ----------------

__global__ __launch_bounds__(256) void aggregate_kernel(
        const ushort_t* __restrict__ zh, const int2* __restrict__ esw,
        const int* __restrict__ offsets, const float* __restrict__ inv_deg,
        ushort_t* __restrict__ aggh) {
    int node = blockIdx.x * 4 + (threadIdx.x >> 6);
    if (node >= NN) return;
    int lane = threadIdx.x & 63;
    const ushort_t* zbase = zh + lane * 8;
    int s0 = offsets[node], s1 = offsets[node + 1];
    float a[8] = {0.f, 0.f, 0.f, 0.f, 0.f, 0.f, 0.f, 0.f};
    int e = s0;
    for (; e + 4 <= s1; e += 4) {
        int2 p0 = esw[e], p1 = esw[e + 1], p2 = esw[e + 2], p3 = esw[e + 3];
        u16x8 v0 = *(const u16x8*)(zbase + (size_t)p0.x * DD);
        u16x8 v1 = *(const u16x8*)(zbase + (size_t)p1.x * DD);
        u16x8 v2 = *(const u16x8*)(zbase + (size_t)p2.x * DD);
        u16x8 v3 = *(const u16x8*)(zbase + (size_t)p3.x * DD);
        float w0 = __int_as_float(p0.y), w1 = __int_as_float(p1.y);
        float w2 = __int_as_float(p2.y), w3 = __int_as_float(p3.y);
        #pragma unroll
        for (int j = 0; j < 8; ++j) {
            a[j] = fmaf(w0, bf2f(v0[j]), a[j]);
            a[j] = fmaf(w1, bf2f(v1[j]), a[j]);
            a[j] = fmaf(w2, bf2f(v2[j]), a[j]);
            a[j] = fmaf(w3, bf2f(v3[j]), a[j]);
        }
    }
    for (; e < s1; ++e) {
        int2 p = esw[e];
        u16x8 v = *(const u16x8*)(zbase + (size_t)p.x * DD);
        float w = __int_as_float(p.y);
        #pragma unroll
        for (int j = 0; j < 8; ++j) a[j] = fmaf(w, bf2f(v[j]), a[j]);
    }
    float inv = inv_deg[node];
    u16x8 o;
    #pragma unroll
    for (int j = 0; j < 8; ++j) o[j] = f2bf(a[j] * inv);
    *(u16x8*)&aggh[(size_t)node * DD + lane * 8] = o;
}

// ---------------- split-bf16 MFMA GEMM ----------------
// out = relu(agg@Wl + z@Wr + b); activations single bf16, weights h/l pair:
// each matmul = A.Bh + A.Bl (2 MFMA products).
// 128x128 tile, BK=64, 4 waves (each 64x64 = 4x4 frags of 16x16x32)

template<bool FINAL>
__global__ __launch_bounds__(256) void gemm_mfma(
        const ushort_t* __restrict__ aggh, const ushort_t* __restrict__ zh,
        const ushort_t* __restrict__ wt,   // this layer: WlTh, WlTl, WrTh, WrTl
        const float* __restrict__ bias,
        ushort_t* __restrict__ outh, float* __restrict__ outf) {
    __shared__ char smem[49152];
    const int AT = 0, BH = 16384, BL = 32768;

    const int tid = threadIdx.x;
    const int lane = tid & 63;
    const int w = tid >> 6;
    const int wr = w >> 1, wc = w & 1;

    // XCD-chunked bijective swizzle (nwg=1564=8*195+4)
    const int orig = blockIdx.y * gridDim.x + blockIdx.x;
    const int q = 195, r = 4;
    const int xcd = orig & 7, kpos = orig >> 3;
    const int wg = (xcd < r ? xcd * (q + 1) : r * (q + 1) + (xcd - r) * q) + kpos;
    const int m0 = (wg >> 2) * 128;
    const int n0 = (wg & 3) * 128;

    // staging: lane covers row q*8+(lane>>3), swizzled 16B slot
    const int rsub = lane >> 3;
    const int sl = (lane & 7) ^ rsub;
    int offA[4], offB[4];
    #pragma unroll
    for (int j = 0; j < 4; ++j) {
        int qq = w * 4 + j;
        int ra = m0 + qq * 8 + rsub;
        if (ra >= NN) ra = NN - 1;          // clamp tail rows (outputs discarded)
        offA[j] = ra * DD + sl * 8;
        int rb = n0 + qq * 8 + rsub;
        offB[j] = rb * DD + sl * 8;
    }

    // ds_read constants
    const int rlo = lane & 15;
    const int khi = lane >> 4;              // 0..3
    const int sw7 = rlo & 7;
    int aRow[4], bRow[4];
    #pragma unroll
    for (int i = 0; i < 4; ++i) {
        aRow[i] = (wr * 64 + i * 16 + rlo) * 128;
        bRow[i] = (wc * 64 + i * 16 + rlo) * 128;
    }

    f32x4 acc[4][4];
    #pragma unroll
    for (int mi = 0; mi < 4; ++mi)
        #pragma unroll
        for (int ni = 0; ni < 4; ++ni)
            acc[mi][ni] = f32x4{0.f, 0.f, 0.f, 0.f};

    #pragma unroll
    for (int pass = 0; pass < 2; ++pass) {
        const ushort_t* A  = pass ? zh : aggh;
        const ushort_t* Bh = wt + (size_t)(pass ? 2 : 0) * DD * DD;
        const ushort_t* Bl = Bh + (size_t)DD * DD;
        for (int k0 = 0; k0 < DD; k0 += 64) {
            #pragma unroll
            for (int j = 0; j < 4; ++j) {
                int qo = (w * 4 + j) * 1024;
                GLD16(A + offA[j] + k0, smem + AT + qo);
                GLD16(Bh + offB[j] + k0, smem + BH + qo);
                GLD16(Bl + offB[j] + k0, smem + BL + qo);
            }
            __syncthreads();
            #pragma unroll
            for (int kk = 0; kk < 2; ++kk) {
                const int pa = ((kk * 4 + khi) ^ sw7) * 16;
                bf16x8 a_f[4], b_h[4], b_l[4];
                #pragma unroll
                for (int i = 0; i < 4; ++i) {
                    a_f[i] = *(const bf16x8*)(smem + AT + aRow[i] + pa);
                    b_h[i] = *(const bf16x8*)(smem + BH + bRow[i] + pa);
                    b_l[i] = *(const bf16x8*)(smem + BL + bRow[i] + pa);
                }
                #pragma unroll
                for (int mi = 0; mi < 4; ++mi)
                    #pragma unroll
                    for (int ni = 0; ni < 4; ++ni) {
                        acc[mi][ni] = __builtin_amdgcn_mfma_f32_16x16x32_bf16(
                            a_f[mi], b_h[ni], acc[mi][ni], 0, 0, 0);
                        acc[mi][ni] = __builtin_amdgcn_mfma_f32_16x16x32_bf16(
                            a_f[mi], b_l[ni], acc[mi][ni], 0, 0, 0);
                    }
            }
            __syncthreads();
        }
    }

    // epilogue: bias + relu; C/D layout col=lane&15, row=(lane>>4)*4+reg
    float bv[4];
    #pragma unroll
    for (int ni = 0; ni < 4; ++ni)
        bv[ni] = bias[n0 + wc * 64 + ni * 16 + rlo];
    #pragma unroll
    for (int mi = 0; mi < 4; ++mi) {
        #pragma unroll
        for (int j = 0; j < 4; ++j) {
            int row = m0 + wr * 64 + mi * 16 + khi * 4 + j;
            if (row < NN) {
                #pragma unroll
                for (int ni = 0; ni < 4; ++ni) {
                    int col = n0 + wc * 64 + ni * 16 + rlo;
                    float v = acc[mi][ni][j] + bv[ni];
                    v = v > 0.f ? v : 0.f;
                    if (FINAL) outf[(size_t)row * DD + col] = v;
                    else       outh[(size_t)row * DD + col] = f2bf(v);
                }
            }
        }
    }
}

extern "C" void kernel_launch(void* const* d_in, const int* in_sizes, int n_in,
                              void* d_out, int out_size, void* d_ws, size_t ws_size,
                              hipStream_t stream) {
    const float* x  = (const float*)d_in[0];
    const int*   ei = (const int*)d_in[1];
    const float* ew = (const float*)d_in[2];
    const float* Wl = (const float*)d_in[3];
    const float* Wr = (const float*)d_in[4];
    const float* b  = (const float*)d_in[5];
    float* out = (float*)d_out;

    const int* srcIdx = ei;
    const int* dstIdx = ei + NE;

    const size_t ND = (size_t)NN * DD;
    char* p = (char*)d_ws;
    ushort_t* zA   = (ushort_t*)p; p += ND * 2;
    ushort_t* zB   = (ushort_t*)p; p += ND * 2;
    ushort_t* aggA = (ushort_t*)p; p += ND * 2;
    ushort_t* wt   = (ushort_t*)p; p += (size_t)12 * DD * DD * 2;
    int* deg      = (int*)p; p += sizeof(int) * NN;
    int* cursor   = (int*)p; p += sizeof(int) * NN;      // contiguous with deg
    int2* esw     = (int2*)p; p += sizeof(int2) * NE;
    float* invdeg = (float*)p; p += sizeof(float) * NN;
    int* offsets  = (int*)p; p += sizeof(int) * (NN + 1);
    int* bsum     = (int*)p; p += sizeof(int) * 64;

    // CSR build
    hipMemsetAsync(deg, 0, sizeof(int) * 2 * NN, stream);
    hist_kernel<<<(NE + 255) / 256, 256, 0, stream>>>(dstIdx, deg);
    scan_local<<<SB, 1024, 0, stream>>>(deg, offsets, bsum);
    scan_carry<<<1, 64, 0, stream>>>(bsum);
    scan_apply<<<SB, 1024, 0, stream>>>(deg, bsum, offsets, invdeg);
    scatter_kernel<<<(NE + 255) / 256, 256, 0, stream>>>(srcIdx, dstIdx, ew, offsets,
                                                          cursor, esw);
    // conversions
    convert_x_kernel<<<2048, 256, 0, stream>>>(x, zA);
    split_wt_kernel<<<dim3(16, 16, 6), dim3(32, 8), 0, stream>>>(Wl, Wr, wt);

    dim3 ggrid(4, MT);
    dim3 agrid((NN + 3) / 4);
    const size_t WTL = (size_t)4 * DD * DD;

    // layer 0: z = zA(x) -> zB
    aggregate_kernel<<<agrid, 256, 0, stream>>>(zA, esw, offsets, invdeg, aggA);
    gemm_mfma<false><<<ggrid, 256, 0, stream>>>(aggA, zA, wt, b, zB, nullptr);
    // layer 1: z = zB -> zA
    aggregate_kernel<<<agrid, 256, 0, stream>>>(zB, esw, offsets, invdeg, aggA);
    gemm_mfma<false><<<ggrid, 256, 0, stream>>>(aggA, zB, wt + WTL, b + DD, zA, nullptr);
    // layer 2: z = zA -> d_out (f32, direct)
    aggregate_kernel<<<agrid, 256, 0, stream>>>(zA, esw, offsets, invdeg, aggA);
    gemm_mfma<true><<<ggrid, 256, 0, stream>>>(aggA, zA, wt + 2 * WTL, b + 2 * DD,
                                               nullptr, out);
}

// Round 5
// 622.674 us; speedup vs baseline: 4.2948x; 1.2034x over previous
//
#include <hip/hip_runtime.h>

#define NN 50000
#define NE 400000
#define DD 512
#define MT 391   // ceil(NN/128)
#define SB 49    // ceil(NN/1024) scan blocks

typedef unsigned short ushort_t;
typedef __attribute__((ext_vector_type(8))) short bf16x8;
typedef __attribute__((ext_vector_type(8))) unsigned short u16x8;
typedef __attribute__((ext_vector_type(4))) float f32x4;

#define GLD16(g, l) __builtin_amdgcn_global_load_lds( \
    (const __attribute__((address_space(1))) void*)(g), \
    (__attribute__((address_space(3))) void*)(l), 16, 0, 0)

__device__ __forceinline__ float bf2f(unsigned short u) {
    union { unsigned u; float f; } c; c.u = ((unsigned)u) << 16; return c.f;
}
__device__ __forceinline__ unsigned short f2bf(float f) {
    union { float f; unsigned u; } c; c.f = f;
    unsigned r = c.u + 0x7FFFu + ((c.u >> 16) & 1u);
    return (unsigned short)(r >> 16);
}

// ---------------- CSR build ----------------

__global__ void hist_kernel(const int* __restrict__ dst, int* __restrict__ deg) {
    int e = blockIdx.x * blockDim.x + threadIdx.x;
    if (e < NE) atomicAdd(&deg[dst[e]], 1);
}

__global__ __launch_bounds__(1024) void scan_local(const int* __restrict__ deg,
                                                   int* __restrict__ offs,
                                                   int* __restrict__ bsum) {
    __shared__ int sdata[1024];
    int i = blockIdx.x * 1024 + threadIdx.x;
    int v = (i < NN) ? deg[i] : 0;
    sdata[threadIdx.x] = v;
    __syncthreads();
    for (int off = 1; off < 1024; off <<= 1) {
        int add = (threadIdx.x >= off) ? sdata[threadIdx.x - off] : 0;
        __syncthreads();
        sdata[threadIdx.x] += add;
        __syncthreads();
    }
    if (i < NN) offs[i] = sdata[threadIdx.x] - v;      // local exclusive
    if (threadIdx.x == 1023) bsum[blockIdx.x] = sdata[1023];
}

__global__ void scan_carry(int* __restrict__ bsum) {    // exclusive scan of SB values
    int lane = threadIdx.x;
    int orig = (lane < SB) ? bsum[lane] : 0;
    int v = orig;
    #pragma unroll
    for (int off = 1; off < 64; off <<= 1) {
        int n = __shfl_up(v, off, 64);
        if (lane >= off) v += n;
    }
    if (lane < SB) bsum[lane] = v - orig;
}

__global__ __launch_bounds__(1024) void scan_apply(const int* __restrict__ deg,
                                                   const int* __restrict__ bsum,
                                                   int* __restrict__ offs,
                                                   float* __restrict__ inv_deg) {
    int i = blockIdx.x * 1024 + threadIdx.x;
    if (i < NN) {
        offs[i] += bsum[blockIdx.x];
        int d = deg[i];
        inv_deg[i] = (d > 0) ? (1.0f / (float)d) : 0.0f;
    }
    if (i == 0) offs[NN] = NE;
}

__global__ void scatter_kernel(const int* __restrict__ src, const int* __restrict__ dst,
                               const float* __restrict__ w, const int* __restrict__ offsets,
                               int* __restrict__ cursor, int2* __restrict__ esw) {
    int e = blockIdx.x * blockDim.x + threadIdx.x;
    if (e < NE) {
        int d = dst[e];
        int pos = offsets[d] + atomicAdd(&cursor[d], 1);
        esw[pos] = make_int2(src[e], __float_as_int(w[e]));
    }
}

// ---------------- input conversions ----------------

__global__ void convert_x_kernel(const float* __restrict__ x, ushort_t* __restrict__ xh) {
    const int total = NN * DD / 8;
    for (int i = blockIdx.x * blockDim.x + threadIdx.x; i < total; i += gridDim.x * blockDim.x) {
        float4 v1 = ((const float4*)x)[2 * i];
        float4 v2 = ((const float4*)x)[2 * i + 1];
        u16x8 o;
        o[0] = f2bf(v1.x); o[1] = f2bf(v1.y); o[2] = f2bf(v1.z); o[3] = f2bf(v1.w);
        o[4] = f2bf(v2.x); o[5] = f2bf(v2.y); o[6] = f2bf(v2.z); o[7] = f2bf(v2.w);
        ((u16x8*)xh)[i] = o;
    }
}

// transpose + convert weights: wt layout [layer][WlT, WrT], each [n][k] bf16
__global__ void convert_wt_kernel(const float* __restrict__ Wl, const float* __restrict__ Wr,
                                  ushort_t* __restrict__ wt) {
    __shared__ float tile[32][33];
    int mat = blockIdx.z;              // layer*2 + (0=Wl,1=Wr)
    int layer = mat >> 1;
    const float* W = (mat & 1) ? (Wr + (size_t)layer * DD * DD) : (Wl + (size_t)layer * DD * DD);
    ushort_t* oh = wt + ((size_t)layer * 2 + (size_t)(mat & 1)) * DD * DD;
    int k0 = blockIdx.y * 32, n0 = blockIdx.x * 32;
    #pragma unroll
    for (int r = 0; r < 4; ++r)
        tile[threadIdx.y * 4 + r][threadIdx.x] =
            W[(size_t)(k0 + threadIdx.y * 4 + r) * DD + n0 + threadIdx.x];
    __syncthreads();
    #pragma unroll
    for (int r = 0; r < 4; ++r) {
        int n = n0 + threadIdx.y * 4 + r, k = k0 + threadIdx.x;
        oh[(size_t)n * DD + k] = f2bf(tile[threadIdx.x][threadIdx.y * 4 + r]);
    }
}

// ---------------- mean aggregation: wave per node, cooperative edge load ----------------
// lanes load 64 edges' (src,w) in one coalesced access, broadcast via shfl;
// row-gather addresses then all independent -> deep MLP.

__global__ __launch_bounds__(256) void aggregate_kernel(
        const ushort_t* __restrict__ zh, const int2* __restrict__ esw,
        const int* __restrict__ offsets, const float* __restrict__ inv_deg,
        ushort_t* __restrict__ aggh) {
    int node = blockIdx.x * 4 + (threadIdx.x >> 6);
    if (node >= NN) return;
    int lane = threadIdx.x & 63;
    const ushort_t* zbase = zh + lane * 8;
    int s0 = offsets[node], s1 = offsets[node + 1];
    float a[8] = {0.f, 0.f, 0.f, 0.f, 0.f, 0.f, 0.f, 0.f};
    for (int base = s0; base < s1; base += 64) {
        int cnt = s1 - base; if (cnt > 64) cnt = 64;
        int2 p = make_int2(0, 0);
        if (base + lane < s1) p = esw[base + lane];
        #pragma unroll 4
        for (int j = 0; j < cnt; ++j) {
            int   s = __shfl(p.x, j);
            float w = __int_as_float(__shfl(p.y, j));
            u16x8 v = *(const u16x8*)(zbase + (size_t)s * DD);
            #pragma unroll
            for (int q = 0; q < 8; ++q) a[q] = fmaf(w, bf2f(v[q]), a[q]);
        }
    }
    float inv = inv_deg[node];
    u16x8 o;
    #pragma unroll
    for (int j = 0; j < 8; ++j) o[j] = f2bf(a[j] * inv);
    *(u16x8*)&aggh[(size_t)node * DD + lane * 8] = o;
}

// ---------------- bf16 MFMA GEMM ----------------
// out = relu(agg@Wl + z@Wr + b); all operands single bf16.
// 128x128 tile, BK=64, 4 waves (each 64x64 = 4x4 frags of 16x16x32)
// LDS: A, B tiles [128 rows][64 bf16 = 128B], XOR slot-swizzled via
// pre-swizzled global source addresses (global_load_lds writes linearly).

template<bool FINAL>
__global__ __launch_bounds__(256) void gemm_mfma(
        const ushort_t* __restrict__ aggh, const ushort_t* __restrict__ zh,
        const ushort_t* __restrict__ wt,   // this layer: WlT, WrT
        const float* __restrict__ bias,
        ushort_t* __restrict__ outh, float* __restrict__ outf) {
    __shared__ char smem[32768];
    const int AT = 0, BT = 16384;

    const int tid = threadIdx.x;
    const int lane = tid & 63;
    const int w = tid >> 6;
    const int wr = w >> 1, wc = w & 1;

    // XCD-chunked bijective swizzle (nwg=1564=8*195+4)
    const int orig = blockIdx.y * gridDim.x + blockIdx.x;
    const int q = 195, r = 4;
    const int xcd = orig & 7, kpos = orig >> 3;
    const int wg = (xcd < r ? xcd * (q + 1) : r * (q + 1) + (xcd - r) * q) + kpos;
    const int m0 = (wg >> 2) * 128;
    const int n0 = (wg & 3) * 128;

    // staging: lane covers row q*8+(lane>>3), swizzled 16B slot
    const int rsub = lane >> 3;
    const int sl = (lane & 7) ^ rsub;
    int offA[4], offB[4];
    #pragma unroll
    for (int j = 0; j < 4; ++j) {
        int qq = w * 4 + j;
        int ra = m0 + qq * 8 + rsub;
        if (ra >= NN) ra = NN - 1;          // clamp tail rows (outputs discarded)
        offA[j] = ra * DD + sl * 8;
        int rb = n0 + qq * 8 + rsub;
        offB[j] = rb * DD + sl * 8;
    }

    // ds_read constants
    const int rlo = lane & 15;
    const int khi = lane >> 4;              // 0..3
    const int sw7 = rlo & 7;
    int aRow[4], bRow[4];
    #pragma unroll
    for (int i = 0; i < 4; ++i) {
        aRow[i] = (wr * 64 + i * 16 + rlo) * 128;
        bRow[i] = (wc * 64 + i * 16 + rlo) * 128;
    }

    f32x4 acc[4][4];
    #pragma unroll
    for (int mi = 0; mi < 4; ++mi)
        #pragma unroll
        for (int ni = 0; ni < 4; ++ni)
            acc[mi][ni] = f32x4{0.f, 0.f, 0.f, 0.f};

    #pragma unroll
    for (int pass = 0; pass < 2; ++pass) {
        const ushort_t* A = pass ? zh : aggh;
        const ushort_t* B = wt + (size_t)pass * DD * DD;
        for (int k0 = 0; k0 < DD; k0 += 64) {
            #pragma unroll
            for (int j = 0; j < 4; ++j) {
                int qo = (w * 4 + j) * 1024;
                GLD16(A + offA[j] + k0, smem + AT + qo);
                GLD16(B + offB[j] + k0, smem + BT + qo);
            }
            __syncthreads();
            #pragma unroll
            for (int kk = 0; kk < 2; ++kk) {
                const int pa = ((kk * 4 + khi) ^ sw7) * 16;
                bf16x8 a_f[4], b_f[4];
                #pragma unroll
                for (int i = 0; i < 4; ++i) {
                    a_f[i] = *(const bf16x8*)(smem + AT + aRow[i] + pa);
                    b_f[i] = *(const bf16x8*)(smem + BT + bRow[i] + pa);
                }
                #pragma unroll
                for (int mi = 0; mi < 4; ++mi)
                    #pragma unroll
                    for (int ni = 0; ni < 4; ++ni)
                        acc[mi][ni] = __builtin_amdgcn_mfma_f32_16x16x32_bf16(
                            a_f[mi], b_f[ni], acc[mi][ni], 0, 0, 0);
            }
            __syncthreads();
        }
    }

    // epilogue: bias + relu; C/D layout col=lane&15, row=(lane>>4)*4+reg
    float bv[4];
    #pragma unroll
    for (int ni = 0; ni < 4; ++ni)
        bv[ni] = bias[n0 + wc * 64 + ni * 16 + rlo];
    #pragma unroll
    for (int mi = 0; mi < 4; ++mi) {
        #pragma unroll
        for (int j = 0; j < 4; ++j) {
            int row = m0 + wr * 64 + mi * 16 + khi * 4 + j;
            if (row < NN) {
                #pragma unroll
                for (int ni = 0; ni < 4; ++ni) {
                    int col = n0 + wc * 64 + ni * 16 + rlo;
                    float v = acc[mi][ni][j] + bv[ni];
                    v = v > 0.f ? v : 0.f;
                    if (FINAL) outf[(size_t)row * DD + col] = v;
                    else       outh[(size_t)row * DD + col] = f2bf(v);
                }
            }
        }
    }
}

extern "C" void kernel_launch(void* const* d_in, const int* in_sizes, int n_in,
                              void* d_out, int out_size, void* d_ws, size_t ws_size,
                              hipStream_t stream) {
    const float* x  = (const float*)d_in[0];
    const int*   ei = (const int*)d_in[1];
    const float* ew = (const float*)d_in[2];
    const float* Wl = (const float*)d_in[3];
    const float* Wr = (const float*)d_in[4];
    const float* b  = (const float*)d_in[5];
    float* out = (float*)d_out;

    const int* srcIdx = ei;
    const int* dstIdx = ei + NE;

    const size_t ND = (size_t)NN * DD;
    char* p = (char*)d_ws;
    ushort_t* zA   = (ushort_t*)p; p += ND * 2;
    ushort_t* zB   = (ushort_t*)p; p += ND * 2;
    ushort_t* aggA = (ushort_t*)p; p += ND * 2;
    ushort_t* wt   = (ushort_t*)p; p += (size_t)6 * DD * DD * 2;
    int* deg      = (int*)p; p += sizeof(int) * NN;
    int* cursor   = (int*)p; p += sizeof(int) * NN;      // contiguous with deg
    int2* esw     = (int2*)p; p += sizeof(int2) * NE;
    float* invdeg = (float*)p; p += sizeof(float) * NN;
    int* offsets  = (int*)p; p += sizeof(int) * (NN + 1);
    int* bsum     = (int*)p; p += sizeof(int) * 64;

    // CSR build
    hipMemsetAsync(deg, 0, sizeof(int) * 2 * NN, stream);
    hist_kernel<<<(NE + 255) / 256, 256, 0, stream>>>(dstIdx, deg);
    scan_local<<<SB, 1024, 0, stream>>>(deg, offsets, bsum);
    scan_carry<<<1, 64, 0, stream>>>(bsum);
    scan_apply<<<SB, 1024, 0, stream>>>(deg, bsum, offsets, invdeg);
    scatter_kernel<<<(NE + 255) / 256, 256, 0, stream>>>(srcIdx, dstIdx, ew, offsets,
                                                          cursor, esw);
    // conversions
    convert_x_kernel<<<2048, 256, 0, stream>>>(x, zA);
    convert_wt_kernel<<<dim3(16, 16, 6), dim3(32, 8), 0, stream>>>(Wl, Wr, wt);

    dim3 ggrid(4, MT);
    dim3 agrid((NN + 3) / 4);
    const size_t WTL = (size_t)2 * DD * DD;

    // layer 0: z = zA(x) -> zB
    aggregate_kernel<<<agrid, 256, 0, stream>>>(zA, esw, offsets, invdeg, aggA);
    gemm_mfma<false><<<ggrid, 256, 0, stream>>>(aggA, zA, wt, b, zB, nullptr);
    // layer 1: z = zB -> zA
    aggregate_kernel<<<agrid, 256, 0, stream>>>(zB, esw, offsets, invdeg, aggA);
    gemm_mfma<false><<<ggrid, 256, 0, stream>>>(aggA, zB, wt + WTL, b + DD, zA, nullptr);
    // layer 2: z = zA -> d_out (f32, direct)
    aggregate_kernel<<<agrid, 256, 0, stream>>>(zA, esw, offsets, invdeg, aggA);
    gemm_mfma<true><<<ggrid, 256, 0, stream>>>(aggA, zA, wt + 2 * WTL, b + 2 * DD,
                                               nullptr, out);
}